// Round 15
// baseline (27.498 us; speedup 1.0000x reference)
//
#include <hip/hip_runtime.h>
#include <math.h>

#define G_N 1024
#define C_N 17
#define NX 200
#define NY 200
#define NZ 16
#define N_VOX (NX * NY * NZ)
#define MAHA_T 7.5f
#define CAP 128   // staged candidates per chunk (loop handles overflow)

// Fused kernel. Super-tile = 8(x) x 8(y) x 16(z), 256 threads, processed as
// 4 sequential SUB-TILES of 2(x) x 8(y) x 16(z) = 256 voxels (1 voxel/thread).
// Cull + stage once (R14-identical); each sub-tile's stores fire as soon as
// it completes -> 4 spaced store bursts that overlap later sub-tiles' compute
// instead of one synchronized terminal burst across all blocks.
__launch_bounds__(256, 4)
__global__ void gv_fused_kernel(const float* __restrict__ means,
                                const float* __restrict__ ops,
                                const float* __restrict__ feats,
                                const float* __restrict__ covs,
                                float* __restrict__ dens_out,
                                float* __restrict__ feat_out) {
    __shared__ unsigned short s_list[G_N];              // 2 KB
    __shared__ __align__(16) float4 s_gd[CAP * 7];      // 14 KB (aliases cull stage)
    __shared__ __align__(16) float  s_out[4 * 64 * C_N];// 17 KB (per-wave slices)
    __shared__ int s_wcnt[4];

    const int tid = threadIdx.x;
    const int wave = tid >> 6;
    const int lane = tid & 63;
    const int bx = blockIdx.x, by = blockIdx.y;

    const float x0 = -40.f + (float)(bx * 8) * 0.4f;
    const float x1 = x0 + 3.2f;
    const float y0 = -40.f + (float)(by * 8) * 0.4f;
    const float y1 = y0 + 3.2f;

    // ---- Phase 1: 4-wave parallel cull (R14-identical, ascending-g) ----
    unsigned short* s_stage = (unsigned short*)s_gd;
    int base = 0;
#pragma unroll
    for (int r = 0; r < 4; ++r) {
        int g = wave * 256 + r * 64 + lane;
        float mx = means[3 * g], my = means[3 * g + 1], mz = means[3 * g + 2];
        float c00 = covs[9 * g], c11 = covs[9 * g + 4], c22 = covs[9 * g + 8];
        float hx = sqrtf(MAHA_T * c00) * 1.01f + 0.01f;
        float hy = sqrtf(MAHA_T * c11) * 1.01f + 0.01f;
        float hz = sqrtf(MAHA_T * c22) * 1.01f + 0.01f;
        bool hit = (mx - hx <= x1) && (mx + hx >= x0) &&
                   (my - hy <= y1) && (my + hy >= y0) &&
                   (mz - hz <= 5.4f) && (mz + hz >= -1.0f);
        unsigned long long m = __ballot(hit);
        int rank = __popcll(m & ((1ull << lane) - 1ull));
        if (hit) s_stage[wave * 256 + base + rank] = (unsigned short)g;
        base += __popcll(m);
    }
    if (lane == 0) s_wcnt[wave] = base;
    __syncthreads();
    const int c0 = s_wcnt[0], c1 = s_wcnt[1], c2 = s_wcnt[2], c3 = s_wcnt[3];
    const int total = c0 + c1 + c2 + c3;
    int off = 0;
    if (wave > 0) off += c0;
    if (wave > 1) off += c1;
    if (wave > 2) off += c2;
    for (int i = lane; i < base; i += 64)
        s_list[off + i] = s_stage[wave * 256 + i];   // ascending-g global order

    const int nchunks = (total + CAP - 1) / CAP;

    // ---- Voxel mapping (per sub-tile s): X = bx*8 + 2s + (tid>>7),
    //      Y = by*8 + ((tid>>4)&7), z = tid&15.  Wave-contiguous outputs. ----
    const int z = tid & 15;
    const int yv = (tid >> 4) & 7;
    const int xh = tid >> 7;             // 0 or 1 within sub-tile
    const int Y = by * 8 + yv;

    float cy, cz;
    {
#pragma clang fp contract(off)
        cy = ((float)Y + 0.5f) * 0.4f + -40.0f;
        cz = ((float)z + 0.5f) * 0.4f + -1.0f;
    }

#define ACC(F, DS, CN, MH) { DS = fmaf(q0.w, __expf(-0.5f * (MH)), DS); CN += 1.f; \
    F[0] += q2.z;  F[1] += q2.w;  F[2] += q3.x;  F[3] += q3.y;  F[4] += q3.z; \
    F[5] += q3.w;  F[6] += q4.x;  F[7] += q4.y;  F[8] += q4.z;  F[9] += q4.w; \
    F[10] += q5.x; F[11] += q5.y; F[12] += q5.z; F[13] += q5.w; F[14] += q6.x; \
    F[15] += q6.y; F[16] += q6.z; }

    // ---- Sub-tile loop: accumulate 1 voxel/thread, store immediately ----
    for (int s = 0; s < 4; ++s) {
        const int X = bx * 8 + 2 * s + xh;
        float cx;
        {
#pragma clang fp contract(off)   // bit-match ref: separate mul/add rounding
            cx = ((float)X + 0.5f) * 0.4f + -40.0f;
        }

        float ds = 0.f, cn = 0.f;
        float fs[C_N];
#pragma unroll
        for (int c = 0; c < C_N; ++c) fs[c] = 0.f;

        for (int cb = 0; cb < total; cb += CAP) {
            const int nc = min(CAP, total - cb);
            if (nchunks > 1 || s == 0) {
                __syncthreads();         // s_gd free (cull stage / prev chunk)
                if (tid < nc) {          // one thread per candidate (fp64 inv)
                    int g = (int)s_list[cb + tid];
                    const float* cv = covs + g * 9;
                    double c00 = cv[0], c01 = cv[1], c02 = cv[2];
                    double c11 = cv[4], c12 = cv[5], c22 = cv[8];
                    double m00 = c11 * c22 - c12 * c12;
                    double m01 = c02 * c12 - c01 * c22;
                    double m02 = c01 * c12 - c02 * c11;
                    double det = c00 * m00 + c01 * m01 + c02 * m02;
                    double inv = 1.0 / det;
                    float a00 = (float)(m00 * inv);
                    float a01 = (float)(m01 * inv);
                    float a02 = (float)(m02 * inv);
                    float a11 = (float)((c00 * c22 - c02 * c02) * inv);
                    float a12 = (float)((c02 * c01 - c00 * c12) * inv);
                    float a22 = (float)((c00 * c11 - c01 * c01) * inv);
                    float mx = means[3 * g], my = means[3 * g + 1], mz = means[3 * g + 2];
                    float op = ops[g];
                    const float* ft = feats + g * C_N;
                    float4* o = s_gd + tid * 7;
                    o[0] = make_float4(mx, my, mz, op);
                    o[1] = make_float4(a00, a11, a22, 2.f * a01);
                    o[2] = make_float4(2.f * a02, 2.f * a12, op * ft[0], op * ft[1]);
                    o[3] = make_float4(op * ft[2], op * ft[3], op * ft[4], op * ft[5]);
                    o[4] = make_float4(op * ft[6], op * ft[7], op * ft[8], op * ft[9]);
                    o[5] = make_float4(op * ft[10], op * ft[11], op * ft[12], op * ft[13]);
                    o[6] = make_float4(op * ft[14], op * ft[15], op * ft[16], 0.f);
                }
                __syncthreads();
            }
            for (int j = 0; j < nc; ++j) {
                const float4* rowp = s_gd + j * 7;
                float4 q0 = rowp[0], q1 = rowp[1], q2 = rowp[2];
                float d0 = cx - q0.x, d1 = cy - q0.y, d2 = cz - q0.z;
                // bit-identical chain to validated R8/R14 form
                float u = fmaf(q1.x, d0, fmaf(q1.w, d1, q2.x * d2));
                float v = fmaf(q1.y, d1, q2.y * d2);
                float w = q1.z * d2;
                float maha = fmaf(d0, u, fmaf(d1, v, d2 * w));
                if (maha <= MAHA_T) {
                    float4 q3 = rowp[3], q4 = rowp[4], q5 = rowp[5], q6 = rowp[6];
                    ACC(fs, ds, cn, maha);
                }
            }
        }

        // ---- Sub-tile epilogue (wave-local, fire-and-forget stores) ----
        const float rd = 1.f / fmaxf(cn, 1.f);
        const int Xw = bx * 8 + 2 * s + (wave >> 1);          // wave's x-column
        const int n0 = 16 * ((by * 8 + 4 * (wave & 1)) + 200 * Xw);
        dens_out[n0 + lane] = ds * rd;                        // contiguous 64

        float* fw = s_out + wave * (64 * C_N);
        const float4* lsrc = (const float4*)fw;
#pragma unroll
        for (int c = 0; c < C_N; ++c) fw[lane * C_N + c] = fs[c] * rd;
        float4* gout = (float4*)(feat_out + (long)n0 * C_N); // 16B-aligned
#pragma unroll
        for (int r = 0; r < 4; ++r) gout[lane + 64 * r] = lsrc[lane + 64 * r];
        if (lane < 16) gout[256 + lane] = lsrc[256 + lane];  // 272 float4
        // no barrier: s_out slice is wave-private, same-wave LDS is in-order;
        // waves free-run into the next sub-tile (desync helps overlap)
    }
}

extern "C" void kernel_launch(void* const* d_in, const int* in_sizes, int n_in,
                              void* d_out, int out_size, void* d_ws, size_t ws_size,
                              hipStream_t stream) {
    const float* means3d     = (const float*)d_in[1];  // [1,G,3]
    const float* opacities   = (const float*)d_in[2];  // [1,G,1]
    const float* features    = (const float*)d_in[3];  // [1,G,C]
    const float* covariances = (const float*)d_in[4];  // [1,G,3,3]

    float* dens_out = (float*)d_out;             // [N]
    float* feat_out = (float*)d_out + N_VOX;     // [N,C]

    dim3 grid(NX / 8, NY / 8);
    gv_fused_kernel<<<grid, 256, 0, stream>>>(means3d, opacities, features,
                                              covariances, dens_out, feat_out);
}